// Round 8
// baseline (301.260 us; speedup 1.0000x reference)
//
#include <hip/hip_runtime.h>
#include <hip/hip_bf16.h>

// WeightedDiceLoss on MI355X -- fused single-pass, bf16 LDS row-ring, round 8:
// 2 output rows per wave-step (2x ILP), barriers halved (8/block), RING=42,
// cheap slot arithmetic (1 modulo/step + conditional wraps).
// input, target: (64,1,512,512) fp32. Output: scalar fp32.
// weight = 1 + 5*|box31(target) - target|; loss = 1 - (2*I+1)/(A+B+1).

#define BATCH 64
#define H     512
#define W     512
#define PADR  15
#define RBAND 32                  // rows per block
#define RING  42                  // live span [8j-15, 8j+26] = 42 rows
#define NBLK  (BATCH * (H / RBAND))   // 1024 blocks

static __device__ __forceinline__ unsigned pack2(float e, float o) {
    __hip_bfloat162 h = __float22bfloat162_rn(make_float2(e, o));
    unsigned u; __builtin_memcpy(&u, &h, 4); return u;
}
static __device__ __forceinline__ float2 unpk(unsigned u) {
    return make_float2(__uint_as_float(u << 16),
                       __uint_as_float(u & 0xffff0000u));
}
static __device__ __forceinline__ int wrapP(int x) {   // x in [0, 2*RING)
    return x >= RING ? x - RING : x;
}
static __device__ __forceinline__ int wrapN(int x) {   // x in (-RING, RING)
    return x < 0 ? x + RING : x;
}

__global__ __launch_bounds__(256, 3) void fused_kernel(const float* __restrict__ tgt,
                                                       const float* __restrict__ inp,
                                                       float4* __restrict__ partials) {
    const int tid  = threadIdx.x;
    const int lane = tid & 63;
    const int wv   = tid >> 6;
    const int blk  = blockIdx.x;
    const int band = blk & 15;               // H/RBAND = 16 bands
    const int b    = blk >> 4;
    const int R0   = band * RBAND;
    const float* timg = tgt + (size_t)b * H * W;
    const float* iimg = inp + (size_t)b * H * W;

    __shared__ __align__(16) unsigned ring[RING * 256];   // 43008 B -> 3 blocks/CU

    const int col0 = lane * 8;
    const int ofs  = lane * 4;

    // ---- preload target rows R0-15 .. R0+26 (42 rows), pack to bf16 -------
    for (int k = 0; k < 11; ++k) {
        const int r_off = wv + 4 * k;
        if (r_off < RING) {
            const int row = R0 - 15 + r_off;   // max 506 < H always
            float4 v0 = make_float4(0.f, 0.f, 0.f, 0.f), v1 = v0;
            if (row >= 0) {
                v0 = *(const float4*)(timg + (size_t)row * W + col0);
                v1 = *(const float4*)(timg + (size_t)row * W + col0 + 4);
            }
            uint4 u;
            u.x = pack2(v0.x, v0.y); u.y = pack2(v0.z, v0.w);
            u.z = pack2(v1.x, v1.y); u.w = pack2(v1.z, v1.w);
            *(uint4*)&ring[((row + RING) % RING) * 256 + ofs] = u;
        }
    }
    __syncthreads();

    const float mL1 = (lane >= 1) ? 1.f : 0.f;
    const float mR1 = (lane <= 62) ? 1.f : 0.f;
    const float mL2 = (lane >= 2) ? 1.f : 0.f;
    const float mR2 = (lane <= 61) ? 1.f : 0.f;

    // ---- init vr centered at row R0+wv ------------------------------------
    float vr[8];
    #pragma unroll
    for (int k = 0; k < 8; ++k) vr[k] = 0.f;
    #pragma unroll
    for (int jj = -PADR; jj <= PADR; ++jj) {
        const int rr = R0 + wv + jj;
        const uint4 c = *(const uint4*)&ring[((rr + RING) % RING) * 256 + ofs];
        const float2 e0 = unpk(c.x), e1 = unpk(c.y), e2 = unpk(c.z), e3 = unpk(c.w);
        vr[0] += e0.x; vr[1] += e0.y; vr[2] += e1.x; vr[3] += e1.y;
        vr[4] += e2.x; vr[5] += e2.y; vr[6] += e3.x; vr[7] += e3.y;
    }

    const float inv = 1.0f / 961.0f;
    float aI = 0.f, aA = 0.f, aB = 0.f;

    for (int j = 0; j < 4; ++j) {
        const int h1 = R0 + 8 * j + wv;      // rows h1 and h1+4 this step
        const int h2 = h1 + 4;
        const int s1 = h1 % RING;            // one modulo per step
        const int s2 = wrapP(s1 + 4);

        // ---- issue all loads up front -------------------------------------
        const float4 i10 = *(const float4*)(iimg + (size_t)h1 * W + col0);
        const float4 i11 = *(const float4*)(iimg + (size_t)h1 * W + col0 + 4);
        const float4 i20 = *(const float4*)(iimg + (size_t)h2 * W + col0);
        const float4 i21 = *(const float4*)(iimg + (size_t)h2 * W + col0 + 4);

        float4 pa0 = make_float4(0.f,0.f,0.f,0.f), pa1 = pa0, pb0 = pa0, pb1 = pa0;
        const int prow1 = R0 + 8 * j + 27 + wv;
        const int prow2 = prow1 + 4;
        if (j < 3) {
            if (prow1 < H) {
                pa0 = *(const float4*)(timg + (size_t)prow1 * W + col0);
                pa1 = *(const float4*)(timg + (size_t)prow1 * W + col0 + 4);
            }
            if (prow2 < H) {
                pb0 = *(const float4*)(timg + (size_t)prow2 * W + col0);
                pb1 = *(const float4*)(timg + (size_t)prow2 * W + col0 + 4);
            }
        }

        const uint4 tc1 = *(const uint4*)&ring[s1 * 256 + ofs];
        const uint4 tc2 = *(const uint4*)&ring[s2 * 256 + ofs];

        // advance A: +h1+16..19, -h1-15..-12 ; advance B: +h1+20..23, -h1-11..-8
        uint4 uaA[4], usA[4], uaB[4], usB[4];
        #pragma unroll
        for (int q = 0; q < 4; ++q) {
            const int arA = h1 + 16 + q;
            uaA[q] = (arA < H) ? *(const uint4*)&ring[wrapP(s1 + 16 + q) * 256 + ofs]
                               : make_uint4(0u,0u,0u,0u);
            usA[q] = *(const uint4*)&ring[wrapN(s1 - 15 + q) * 256 + ofs];
        }
        if (j < 3) {
            #pragma unroll
            for (int q = 0; q < 4; ++q) {
                const int arB = h1 + 20 + q;
                uaB[q] = (arB < H) ? *(const uint4*)&ring[wrapP(s1 + 20 + q) * 256 + ofs]
                                   : make_uint4(0u,0u,0u,0u);
                usB[q] = *(const uint4*)&ring[wrapN(s1 - 11 + q) * 256 + ofs];
            }
        }

        // ==== row h1: window + products ====================================
        {
            const float p1 = vr[0];
            const float p2 = p1 + vr[1];
            const float p3 = p2 + vr[2];
            const float p4 = p3 + vr[3];
            const float p5 = p4 + vr[4];
            const float p6 = p5 + vr[5];
            const float p7 = p6 + vr[6];
            const float s  = p7 + vr[7];
            const float f1 = s - p1, f2 = s - p2, f3 = s - p3, f4 = s - p4;
            const float f5 = s - p5, f6 = s - p6, f7 = s - p7;

            const float sL1 = __shfl_up(s, 1, 64);
            const float sR1 = __shfl_down(s, 1, 64);
            const float g1 = __shfl_up(f1, 2, 64), g2 = __shfl_up(f2, 2, 64);
            const float g3 = __shfl_up(f3, 2, 64), g4 = __shfl_up(f4, 2, 64);
            const float g5 = __shfl_up(f5, 2, 64), g6 = __shfl_up(f6, 2, 64);
            const float g7 = __shfl_up(f7, 2, 64);
            const float q1 = __shfl_down(p1, 2, 64), q2 = __shfl_down(p2, 2, 64);
            const float q3 = __shfl_down(p3, 2, 64), q4 = __shfl_down(p4, 2, 64);
            const float q5 = __shfl_down(p5, 2, 64), q6 = __shfl_down(p6, 2, 64);
            const float q7 = __shfl_down(p7, 2, 64);

            const float S3 = fmaf(mL1, sL1, fmaf(mR1, sR1, s));
            float win[8];
            win[0] = fmaf(mL2, g1, S3);
            win[1] = fmaf(mL2, g2, fmaf(mR2, q1, S3));
            win[2] = fmaf(mL2, g3, fmaf(mR2, q2, S3));
            win[3] = fmaf(mL2, g4, fmaf(mR2, q3, S3));
            win[4] = fmaf(mL2, g5, fmaf(mR2, q4, S3));
            win[5] = fmaf(mL2, g6, fmaf(mR2, q5, S3));
            win[6] = fmaf(mL2, g7, fmaf(mR2, q6, S3));
            win[7] = fmaf(mR2, q7, S3);

            const float2 t0 = unpk(tc1.x), t1 = unpk(tc1.y),
                         t2 = unpk(tc1.z), t3 = unpk(tc1.w);
            const float tv[8] = {t0.x,t0.y,t1.x,t1.y,t2.x,t2.y,t3.x,t3.y};
            const float iv[8] = {i10.x,i10.y,i10.z,i10.w,i11.x,i11.y,i11.z,i11.w};
            #pragma unroll
            for (int k = 0; k < 8; ++k) {
                const float wgt = fmaf(5.0f, fabsf(fmaf(win[k], inv, -tv[k])), 1.0f);
                aI += iv[k] * tv[k] * wgt;
                aA += iv[k] * wgt;
                aB += tv[k] * wgt;
            }
        }

        // ---- advance A -----------------------------------------------------
        #pragma unroll
        for (int q = 0; q < 4; ++q) {
            const float2 a0 = unpk(uaA[q].x), a1 = unpk(uaA[q].y),
                         a2 = unpk(uaA[q].z), a3 = unpk(uaA[q].w);
            const float2 s0 = unpk(usA[q].x), s1v = unpk(usA[q].y),
                         s2v = unpk(usA[q].z), s3v = unpk(usA[q].w);
            vr[0] += a0.x - s0.x;  vr[1] += a0.y - s0.y;
            vr[2] += a1.x - s1v.x; vr[3] += a1.y - s1v.y;
            vr[4] += a2.x - s2v.x; vr[5] += a2.y - s2v.y;
            vr[6] += a3.x - s3v.x; vr[7] += a3.y - s3v.y;
        }

        // ==== row h2: window + products ====================================
        {
            const float p1 = vr[0];
            const float p2 = p1 + vr[1];
            const float p3 = p2 + vr[2];
            const float p4 = p3 + vr[3];
            const float p5 = p4 + vr[4];
            const float p6 = p5 + vr[5];
            const float p7 = p6 + vr[6];
            const float s  = p7 + vr[7];
            const float f1 = s - p1, f2 = s - p2, f3 = s - p3, f4 = s - p4;
            const float f5 = s - p5, f6 = s - p6, f7 = s - p7;

            const float sL1 = __shfl_up(s, 1, 64);
            const float sR1 = __shfl_down(s, 1, 64);
            const float g1 = __shfl_up(f1, 2, 64), g2 = __shfl_up(f2, 2, 64);
            const float g3 = __shfl_up(f3, 2, 64), g4 = __shfl_up(f4, 2, 64);
            const float g5 = __shfl_up(f5, 2, 64), g6 = __shfl_up(f6, 2, 64);
            const float g7 = __shfl_up(f7, 2, 64);
            const float q1 = __shfl_down(p1, 2, 64), q2 = __shfl_down(p2, 2, 64);
            const float q3 = __shfl_down(p3, 2, 64), q4 = __shfl_down(p4, 2, 64);
            const float q5 = __shfl_down(p5, 2, 64), q6 = __shfl_down(p6, 2, 64);
            const float q7 = __shfl_down(p7, 2, 64);

            const float S3 = fmaf(mL1, sL1, fmaf(mR1, sR1, s));
            float win[8];
            win[0] = fmaf(mL2, g1, S3);
            win[1] = fmaf(mL2, g2, fmaf(mR2, q1, S3));
            win[2] = fmaf(mL2, g3, fmaf(mR2, q2, S3));
            win[3] = fmaf(mL2, g4, fmaf(mR2, q3, S3));
            win[4] = fmaf(mL2, g5, fmaf(mR2, q4, S3));
            win[5] = fmaf(mL2, g6, fmaf(mR2, q5, S3));
            win[6] = fmaf(mL2, g7, fmaf(mR2, q6, S3));
            win[7] = fmaf(mR2, q7, S3);

            const float2 t0 = unpk(tc2.x), t1 = unpk(tc2.y),
                         t2 = unpk(tc2.z), t3 = unpk(tc2.w);
            const float tv[8] = {t0.x,t0.y,t1.x,t1.y,t2.x,t2.y,t3.x,t3.y};
            const float iv[8] = {i20.x,i20.y,i20.z,i20.w,i21.x,i21.y,i21.z,i21.w};
            #pragma unroll
            for (int k = 0; k < 8; ++k) {
                const float wgt = fmaf(5.0f, fabsf(fmaf(win[k], inv, -tv[k])), 1.0f);
                aI += iv[k] * tv[k] * wgt;
                aA += iv[k] * wgt;
                aB += tv[k] * wgt;
            }
        }

        // ---- advance B + publish (skipped on last step) --------------------
        if (j < 3) {
            #pragma unroll
            for (int q = 0; q < 4; ++q) {
                const float2 a0 = unpk(uaB[q].x), a1 = unpk(uaB[q].y),
                             a2 = unpk(uaB[q].z), a3 = unpk(uaB[q].w);
                const float2 s0 = unpk(usB[q].x), s1v = unpk(usB[q].y),
                             s2v = unpk(usB[q].z), s3v = unpk(usB[q].w);
                vr[0] += a0.x - s0.x;  vr[1] += a0.y - s0.y;
                vr[2] += a1.x - s1v.x; vr[3] += a1.y - s1v.y;
                vr[4] += a2.x - s2v.x; vr[5] += a2.y - s2v.y;
                vr[6] += a3.x - s3v.x; vr[7] += a3.y - s3v.y;
            }
            __syncthreads();
            if (prow1 < H) {
                uint4 u;
                u.x = pack2(pa0.x, pa0.y); u.y = pack2(pa0.z, pa0.w);
                u.z = pack2(pa1.x, pa1.y); u.w = pack2(pa1.z, pa1.w);
                *(uint4*)&ring[(prow1 % RING) * 256 + ofs] = u;
            }
            if (prow2 < H) {
                uint4 u;
                u.x = pack2(pb0.x, pb0.y); u.y = pack2(pb0.z, pb0.w);
                u.z = pack2(pb1.x, pb1.y); u.w = pack2(pb1.z, pb1.w);
                *(uint4*)&ring[(prow2 % RING) * 256 + ofs] = u;
            }
            __syncthreads();
        }
    }

    // wave reduction (64 lanes)
    #pragma unroll
    for (int off = 32; off > 0; off >>= 1) {
        aI += __shfl_down(aI, off, 64);
        aA += __shfl_down(aA, off, 64);
        aB += __shfl_down(aB, off, 64);
    }
    __syncthreads();                          // ring reads done before reuse
    float* rf = (float*)ring;
    if (lane == 0) { rf[wv] = aI; rf[8 + wv] = aA; rf[16 + wv] = aB; }
    __syncthreads();
    if (tid == 0) {
        float4 o;
        o.x = rf[0] + rf[1] + rf[2] + rf[3];
        o.y = rf[8] + rf[9] + rf[10] + rf[11];
        o.z = rf[16] + rf[17] + rf[18] + rf[19];
        o.w = 0.f;
        partials[blk] = o;
    }
}

// ---------------------------------------------------------------------------
// Reduce NBLK (1024) partials + finalize. One block, 1024 threads (16 waves).
// ---------------------------------------------------------------------------
__global__ __launch_bounds__(1024) void reduce_kernel(const float4* __restrict__ partials,
                                                      float* __restrict__ out) {
    const int tid = threadIdx.x;
    const float4 v = partials[tid];          // exactly 1024 entries
    float aI = v.x, aA = v.y, aB = v.z;
    #pragma unroll
    for (int off = 32; off > 0; off >>= 1) {
        aI += __shfl_down(aI, off, 64);
        aA += __shfl_down(aA, off, 64);
        aB += __shfl_down(aB, off, 64);
    }
    __shared__ float s[3][16];
    const int wvx = tid >> 6, ln = tid & 63;
    if (ln == 0) { s[0][wvx] = aI; s[1][wvx] = aA; s[2][wvx] = aB; }
    __syncthreads();
    if (tid == 0) {
        float I = 0.f, A = 0.f, Bv = 0.f;
        #pragma unroll
        for (int k = 0; k < 16; ++k) { I += s[0][k]; A += s[1][k]; Bv += s[2][k]; }
        out[0] = 1.0f - (2.0f * I + 1.0f) / (A + Bv + 1.0f);
    }
}

extern "C" void kernel_launch(void* const* d_in, const int* in_sizes, int n_in,
                              void* d_out, int out_size, void* d_ws, size_t ws_size,
                              hipStream_t stream) {
    const float* inp = (const float*)d_in[0];   // "input"
    const float* tgt = (const float*)d_in[1];   // "target"
    float* out = (float*)d_out;

    float4* partials = (float4*)d_ws;

    fused_kernel<<<NBLK, 256, 0, stream>>>(tgt, inp, partials);
    reduce_kernel<<<1, 1024, 0, stream>>>(partials, out);
}